// Round 7
// baseline (1959.460 us; speedup 1.0000x reference)
//
#include <hip/hip_runtime.h>
#include <hip/hip_bf16.h>
#include <hip/hip_fp16.h>

// Problem constants
#define BB 64
#define SS 512
#define HH 512
#define EE 512

typedef _Float16 h2 __attribute__((ext_vector_type(2)));
typedef _Float16 f16x8 __attribute__((ext_vector_type(8)));
typedef float f32x4 __attribute__((ext_vector_type(4)));

static __device__ inline h2 bch2(unsigned int x) {
  return __builtin_bit_cast(h2, x);
}

static __device__ inline float dot2f(h2 a, h2 b, float c) {
#if __has_builtin(__builtin_amdgcn_fdot2)
  return __builtin_amdgcn_fdot2(a, b, c, false);
#else
  return c + (float)a[0] * (float)b[0] + (float)a[1] * (float)b[1];
#endif
}

static __device__ inline float tanhf_fast(float x) {
  float e = __expf(2.0f * x);
  return 1.0f - 2.0f / (e + 1.0f);
}

static __device__ inline h2 cvt2(float2 f) {
  h2 v;
  v[0] = (_Float16)f.x;
  v[1] = (_Float16)f.y;
  return v;
}

static __device__ inline f16x8 cvt8(float4 f0, float4 f1) {
  return (f16x8){(_Float16)f0.x, (_Float16)f0.y, (_Float16)f0.z, (_Float16)f0.w,
                 (_Float16)f1.x, (_Float16)f1.y, (_Float16)f1.z, (_Float16)f1.w};
}

// ---------------------------------------------------------------------------
// MFMA GEMM: out[m][n] = sum_k A[m][k]*W[n][k] + bias0[n] + bias1[n]
// (unchanged from round 5 — ~100 us each)
// ---------------------------------------------------------------------------
template <bool GATHER>
__global__ __launch_bounds__(256) void gemm_mfma(
    const _Float16* __restrict__ Af16, const int* __restrict__ tokens,
    const float* __restrict__ emb, const float* __restrict__ W,
    const float* __restrict__ bias0, const float* __restrict__ bias1,
    float* __restrict__ out) {
  __shared__ f16x8 wlds[128 * 64];  // [n_loc][slot], slot=(k/8)^(n_loc&7); 128KB
  const int tid = threadIdx.x;
  const int mg = blockIdx.x;       // 64 M-groups of 512 rows
  const int n0 = blockIdx.y * 128; // 4 N-groups

  {
    const int n_loc = tid >> 1;  // 0..127
    const int kh = tid & 1;      // k half (256 each)
    const float4* wrow = (const float4*)(W + (long)(n0 + n_loc) * HH + kh * 256);
#pragma unroll
    for (int i = 0; i < 32; ++i) {
      f16x8 v = cvt8(wrow[2 * i], wrow[2 * i + 1]);
      const int slog = kh * 32 + i;
      wlds[n_loc * 64 + (slog ^ (n_loc & 7))] = v;
    }
  }
  __syncthreads();

  const int w = tid >> 6;
  const int l = tid & 63;
  const int lr = l & 15;
  const int cg = l >> 4;

  float bsum[8];
#pragma unroll
  for (int nt = 0; nt < 8; ++nt) {
    const int n = n0 + nt * 16 + lr;
    bsum[nt] = bias0[n] + bias1[n];
  }

  for (int mt = 0; mt < 8; ++mt) {
    const int m0 = mg * 512 + w * 128 + mt * 16;
    const int row = m0 + lr;
    const float* arow_f32 = nullptr;
    const _Float16* arow_f16 = nullptr;
    if constexpr (GATHER) {
      arow_f32 = emb + (long)tokens[row] * EE;
    } else {
      arow_f16 = Af16 + (long)row * HH;
    }

    f32x4 acc[8] = {{0.f, 0.f, 0.f, 0.f}, {0.f, 0.f, 0.f, 0.f},
                    {0.f, 0.f, 0.f, 0.f}, {0.f, 0.f, 0.f, 0.f},
                    {0.f, 0.f, 0.f, 0.f}, {0.f, 0.f, 0.f, 0.f},
                    {0.f, 0.f, 0.f, 0.f}, {0.f, 0.f, 0.f, 0.f}};
#pragma unroll
    for (int kt = 0; kt < 16; ++kt) {
      f16x8 af;
      if constexpr (GATHER) {
        const float4* p = (const float4*)(arow_f32 + kt * 32 + cg * 8);
        af = cvt8(p[0], p[1]);
      } else {
        af = *(const f16x8*)(arow_f16 + kt * 32 + cg * 8);
      }
#pragma unroll
      for (int nt = 0; nt < 8; ++nt) {
        f16x8 bf = wlds[(nt * 16 + lr) * 64 + ((kt * 4 + cg) ^ (lr & 7))];
        acc[nt] = __builtin_amdgcn_mfma_f32_16x16x32_f16(af, bf, acc[nt], 0, 0, 0);
      }
    }
#pragma unroll
    for (int nt = 0; nt < 8; ++nt) {
      const int n = n0 + nt * 16 + lr;
#pragma unroll
      for (int j = 0; j < 4; ++j) {
        const int m = m0 + cg * 4 + j;
        out[(long)m * HH + n] = acc[nt][j] + bsum[nt];
      }
    }
  }
}

// ---------------------------------------------------------------------------
// Recurrence v5: h_t = tanh(xw_t + W_hh h_{t-1}). One wg / batch elem, 512
// thr. K-SPLIT mapping (round-6 diagnosis: old kernel was LDS-pipe-bound,
// ~2000 cyc/step of broadcast h-reads): thread (w,g,s) with g=lane>>2,
// s=lane&3 computes 4 rows {64w+4g+0..3} over k-slice [128s,128s+128).
// h reads/thread: 16 uint4 (4 distinct addrs/instr, conflict-free via 272B
// slice stagger) instead of 64 broadcasts. Partial sums reduced over the 4
// slots via 2 shfl_xor stages (DPP -> VALU pipe). W per thread = 512 f16:
// 448 in regs (VGPR+AGPR), 64 in LDS (full-BW b128 pattern).
// ---------------------------------------------------------------------------
__global__ __launch_bounds__(512, 2) void rec_v5(
    const float* __restrict__ Whh,  // [512][512] f32
    const float* __restrict__ xw,   // [B*S][512] f32
    _Float16* __restrict__ hout     // [B*S][512] f16
) {
  extern __shared__ char smem[];
  uint4* wlds = (uint4*)smem;            // [8][512] uint4 = 64 KB
  char* hs0 = smem + 8 * 512 * 16;       // h buffers: 2 x 1088 B (4 x 272)
  char* hs1 = hs0 + 1088;

  const int tid = threadIdx.x;
  const int wv = tid >> 6;
  const int l = tid & 63;
  const int g = l >> 2;   // 0..15
  const int s = l & 3;    // k-slice
  const int base_row = 64 * wv + 4 * g;
  const int b = blockIdx.x;
  const long base = (long)b * SS;

  // ---- setup: W fragments ----
  h2 w0[64], w1[64], w2[64], w3h[32];
  {
    const float2* src0 = (const float2*)(Whh + (long)(base_row + 0) * HH + 128 * s);
    const float2* src1 = (const float2*)(Whh + (long)(base_row + 1) * HH + 128 * s);
    const float2* src2 = (const float2*)(Whh + (long)(base_row + 2) * HH + 128 * s);
#pragma unroll
    for (int q = 0; q < 64; ++q) {
      w0[q] = cvt2(src0[q]);
      w1[q] = cvt2(src1[q]);
      w2[q] = cvt2(src2[q]);
    }
    const float2* src3 = (const float2*)(Whh + (long)(base_row + 3) * HH + 128 * s);
#pragma unroll
    for (int q = 0; q < 32; ++q) w3h[q] = cvt2(src3[q]);
    const float4* s4 = (const float4*)(Whh + (long)(base_row + 3) * HH + 128 * s + 64);
#pragma unroll
    for (int j = 0; j < 8; ++j)
      wlds[j * 512 + tid] = __builtin_bit_cast(uint4, cvt8(s4[2 * j], s4[2 * j + 1]));
  }
  // h_{-1} = 0 in buffer 0; h value k lives at 272*(k>>7) + 2*(k&127)
  *(_Float16*)(hs0 + 272 * (tid >> 7) + 2 * (tid & 127)) = (_Float16)0.f;
  __syncthreads();

  float xwv = xw[base * HH + tid];
  float hval_prev = 0.f;

  for (int t = 0; t < SS; ++t) {
    if (t > 0) hout[(base + t - 1) * HH + tid] = (_Float16)hval_prev;
    float xw_next = (t + 1 < SS) ? xw[(base + t + 1) * HH + tid] : 0.f;

    const char* hc = (t & 1) ? hs1 : hs0;
    char* hn = (t & 1) ? hs0 : hs1;
    const uint4* hslice = (const uint4*)(hc + 272 * s);

    float p0 = 0.f, p1 = 0.f, p2 = 0.f, p3 = 0.f;
#pragma unroll
    for (int j = 0; j < 16; ++j) {
      uint4 u = hslice[j];
      p0 = dot2f(w0[4 * j + 0], bch2(u.x), p0);
      p0 = dot2f(w0[4 * j + 1], bch2(u.y), p0);
      p0 = dot2f(w0[4 * j + 2], bch2(u.z), p0);
      p0 = dot2f(w0[4 * j + 3], bch2(u.w), p0);
      p1 = dot2f(w1[4 * j + 0], bch2(u.x), p1);
      p1 = dot2f(w1[4 * j + 1], bch2(u.y), p1);
      p1 = dot2f(w1[4 * j + 2], bch2(u.z), p1);
      p1 = dot2f(w1[4 * j + 3], bch2(u.w), p1);
      p2 = dot2f(w2[4 * j + 0], bch2(u.x), p2);
      p2 = dot2f(w2[4 * j + 1], bch2(u.y), p2);
      p2 = dot2f(w2[4 * j + 2], bch2(u.z), p2);
      p2 = dot2f(w2[4 * j + 3], bch2(u.w), p2);
      if (j < 8) {
        p3 = dot2f(w3h[4 * j + 0], bch2(u.x), p3);
        p3 = dot2f(w3h[4 * j + 1], bch2(u.y), p3);
        p3 = dot2f(w3h[4 * j + 2], bch2(u.z), p3);
        p3 = dot2f(w3h[4 * j + 3], bch2(u.w), p3);
      } else {
        uint4 wvx = wlds[(j - 8) * 512 + tid];
        p3 = dot2f(bch2(wvx.x), bch2(u.x), p3);
        p3 = dot2f(bch2(wvx.y), bch2(u.y), p3);
        p3 = dot2f(bch2(wvx.z), bch2(u.z), p3);
        p3 = dot2f(bch2(wvx.w), bch2(u.w), p3);
      }
    }
    // reduce over the 4 k-slices (lanes s=0..3 within each 4-lane group)
#pragma unroll
    for (int st = 1; st <= 2; st <<= 1) {
      p0 += __shfl_xor(p0, st);
      p1 += __shfl_xor(p1, st);
      p2 += __shfl_xor(p2, st);
      p3 += __shfl_xor(p3, st);
    }
    // select this lane's row (base_row + s == tid)
    float pa = (s & 1) ? p1 : p0;
    float pb = (s & 1) ? p3 : p2;
    float pv = (s & 2) ? pb : pa;
    float hval = tanhf_fast(xwv + pv);

    *(_Float16*)(hn + 272 * (tid >> 7) + 2 * (tid & 127)) = (_Float16)hval;
    __syncthreads();
    xwv = xw_next;
    hval_prev = hval;
  }
  hout[(base + SS - 1) * HH + tid] = (_Float16)hval_prev;
}

// out[m][c] = sum_h h1[m][h] * Wfc[c][h] + bfc[c];  one wave per row m
__global__ __launch_bounds__(256) void fc_kernel(
    const _Float16* __restrict__ h1, const float* __restrict__ Wfc,
    const float* __restrict__ bfc, float* __restrict__ out) {
  const int lane = threadIdx.x & 63;
  const int wid = threadIdx.x >> 6;
  const long m = (long)blockIdx.x * 4 + wid;
  f16x8 hv = ((const f16x8*)(h1 + m * HH))[lane];
  const float4* w0 = (const float4*)(Wfc);
  const float4* w1 = (const float4*)(Wfc + HH);
  float4 a0 = w0[2 * lane], a1 = w0[2 * lane + 1];
  float4 b0 = w1[2 * lane], b1 = w1[2 * lane + 1];
  float p0 = (float)hv[0] * a0.x + (float)hv[1] * a0.y + (float)hv[2] * a0.z +
             (float)hv[3] * a0.w + (float)hv[4] * a1.x + (float)hv[5] * a1.y +
             (float)hv[6] * a1.z + (float)hv[7] * a1.w;
  float p1 = (float)hv[0] * b0.x + (float)hv[1] * b0.y + (float)hv[2] * b0.z +
             (float)hv[3] * b0.w + (float)hv[4] * b1.x + (float)hv[5] * b1.y +
             (float)hv[6] * b1.z + (float)hv[7] * b1.w;
#pragma unroll
  for (int off = 32; off; off >>= 1) {
    p0 += __shfl_down(p0, off);
    p1 += __shfl_down(p1, off);
  }
  if (lane == 0) {
    out[m * 2 + 0] = p0 + bfc[0];
    out[m * 2 + 1] = p1 + bfc[1];
  }
}

extern "C" void kernel_launch(void* const* d_in, const int* in_sizes, int n_in,
                              void* d_out, int out_size, void* d_ws, size_t ws_size,
                              hipStream_t stream) {
  const int* tokens = (const int*)d_in[0];
  const float* emb = (const float*)d_in[1];
  const float* W_ih0 = (const float*)d_in[2];
  const float* b_ih0 = (const float*)d_in[3];
  const float* W_hh0 = (const float*)d_in[4];
  const float* b_hh0 = (const float*)d_in[5];
  const float* W_ih1 = (const float*)d_in[6];
  const float* b_ih1 = (const float*)d_in[7];
  const float* W_hh1 = (const float*)d_in[8];
  const float* b_hh1 = (const float*)d_in[9];
  const float* W_fc = (const float*)d_in[10];
  const float* b_fc = (const float*)d_in[11];
  float* out = (float*)d_out;

  const long MS = (long)BB * SS;                 // 32768
  float* bufA = (float*)d_ws;                    // xw [MS][512] f32 (64MB)
  _Float16* bufB = (_Float16*)(bufA + MS * HH);  // h  [MS][512] f16 (32MB)

  const int rec_lds = 8 * 512 * 16 + 2 * 1088;  // 67712 B

  // xw0 = gather(emb, tokens) @ W_ih0^T + b_ih0 + b_hh0
  gemm_mfma<true><<<dim3(64, 4), 256, 0, stream>>>(
      nullptr, tokens, emb, W_ih0, b_ih0, b_hh0, bufA);
  // layer 0 recurrence -> h0 (f16) in bufB
  rec_v5<<<64, 512, rec_lds, stream>>>(W_hh0, bufA, bufB);
  // xw1 = h0 @ W_ih1^T + b_ih1 + b_hh1  (A = h0 f16)
  gemm_mfma<false><<<dim3(64, 4), 256, 0, stream>>>(
      bufB, nullptr, nullptr, W_ih1, b_ih1, b_hh1, bufA);
  // layer 1 recurrence -> h1 (f16) in bufB
  rec_v5<<<64, 512, rec_lds, stream>>>(W_hh1, bufA, bufB);
  // FC
  fc_kernel<<<8192, 256, 0, stream>>>(bufB, W_fc, b_fc, out);
}